// Round 8
// baseline (144.873 us; speedup 1.0000x reference)
//
#include <hip/hip_runtime.h>
#include <hip/hip_bf16.h>

#define D     64    // feature dim == units
#define CH    4096  // edges per chunk (bin)
#define NPB   32    // nodes per aggregate block
#define CAP   64    // slab capacity per node (deg ~Poisson(16), max<<64)
#define CAPSH 6     // log2(CAP)

// ---------------------------------------------------------------------------
// front: blocks [0,NC): bin edges into PER-NODE slabs.  pos comes from a
// per-node global atomicAdd (depth ~16 per address -> ~4us tail by the
// session's 230ns/queued-RMW contention model; R4's 130us was depth-512).
// No LDS, no barriers in this branch.
// Blocks [NC,NC+gemmTiles): Z = emb @ W (bf16 out), proven R0 tile.
// ---------------------------------------------------------------------------
__global__ __launch_bounds__(256) void front(
    const float* __restrict__ emb,
    const float* __restrict__ W,
    __hip_bfloat16* __restrict__ Zb,
    const int*   __restrict__ src,
    const int*   __restrict__ dst,
    const float* __restrict__ w,
    int*         __restrict__ gcnt,   // [N], pre-zeroed by memset
    int2*        __restrict__ csr,    // [N * CAP] per-node slabs
    int N, int E, int NC)
{
    __shared__ float At[4096];   // 16 KB, GEMM branch only

    const int t = threadIdx.x;

    if ((int)blockIdx.x < NC) {
        const int e0  = (int)blockIdx.x * CH;
        const int cnt = min(CH, E - e0);   // multiple of 4 (E%4==0)
        const int4*   s4p = reinterpret_cast<const int4*>(src + e0);
        const int4*   d4p = reinterpret_cast<const int4*>(dst + e0);
        const float4* w4p = reinterpret_cast<const float4*>(w + e0);
#pragma unroll
        for (int i = 0; i < 4; ++i) {
            int g = i * 256 + t;
            if (g * 4 < cnt) {
                int4   s4 = s4p[g];
                int4   d4 = d4p[g];
                float4 w4 = w4p[g];
                // 4 independent atomic-return chains (distinct addrs w.h.p.)
                int p0 = atomicAdd(&gcnt[d4.x], 1);
                int p1 = atomicAdd(&gcnt[d4.y], 1);
                int p2 = atomicAdd(&gcnt[d4.z], 1);
                int p3 = atomicAdd(&gcnt[d4.w], 1);
                csr[((size_t)d4.x << CAPSH) + p0] = make_int2(s4.x, __float_as_int(w4.x));
                csr[((size_t)d4.y << CAPSH) + p1] = make_int2(s4.y, __float_as_int(w4.y));
                csr[((size_t)d4.z << CAPSH) + p2] = make_int2(s4.z, __float_as_int(w4.z));
                csr[((size_t)d4.w << CAPSH) + p3] = make_int2(s4.w, __float_as_int(w4.w));
            }
        }
        return;
    }

    // ---- GEMM branch: tile (blockIdx.x - NC), proven R0 body --------------
    const int row0 = ((int)blockIdx.x - NC) * 64;
    const int lane = t & 63;
    const int wave = t >> 6;

    float wcol[D];
#pragma unroll
    for (int k = 0; k < D; ++k) wcol[k] = W[k * D + lane];

    for (int i = t; i < 1024; i += 256) {
        int r = i >> 4, gr = row0 + r;
        float4 v = (gr < N)
            ? reinterpret_cast<const float4*>(emb)[(size_t)gr * 16 + (i & 15)]
            : float4{0.f, 0.f, 0.f, 0.f};
        reinterpret_cast<float4*>(At)[i] = v;
    }
    __syncthreads();

    for (int rr = 0; rr < 16; ++rr) {
        int r = wave * 16 + rr, gr = row0 + r;
        if (gr >= N) break;
        const float4* arow = reinterpret_cast<const float4*>(At + r * D);
        float acc = 0.f;
#pragma unroll
        for (int k4 = 0; k4 < 16; ++k4) {
            float4 a = arow[k4];
            acc = fmaf(a.x, wcol[4 * k4 + 0], acc);
            acc = fmaf(a.y, wcol[4 * k4 + 1], acc);
            acc = fmaf(a.z, wcol[4 * k4 + 2], acc);
            acc = fmaf(a.w, wcol[4 * k4 + 3], acc);
        }
        Zb[(size_t)gr * D + lane] = __float2bfloat16(acc);
    }
}

// ---------------------------------------------------------------------------
// aggregate: pure slab-walk — NO LDS, NO barriers, no sort.  One wave owns
// 8 nodes sequentially; 8 slots x 8 q-lanes, 3-deep prefetch (proven gather
// body), cross-slot shfl reduce, coalesced 256B row store.
// ---------------------------------------------------------------------------
__global__ __launch_bounds__(256) void aggregate(
    const __hip_bfloat16* __restrict__ Zb,
    const int2* __restrict__ csr,
    const int*  __restrict__ gcnt,
    float*      __restrict__ out,
    int N)
{
    const int t    = threadIdx.x;
    const int wv   = t >> 6, lane = t & 63, slot = lane >> 3, q = lane & 7;
    const int4* Zq = reinterpret_cast<const int4*>(Zb);   // bf16 row = 8 int4

#define FMA8(LO, HI, WW, ZZ)                                                     \
    do {                                                                         \
        (LO).x = fmaf((WW), __uint_as_float((unsigned)(ZZ).x << 16),        (LO).x); \
        (LO).y = fmaf((WW), __uint_as_float((unsigned)(ZZ).x & 0xFFFF0000u),(LO).y); \
        (LO).z = fmaf((WW), __uint_as_float((unsigned)(ZZ).y << 16),        (LO).z); \
        (LO).w = fmaf((WW), __uint_as_float((unsigned)(ZZ).y & 0xFFFF0000u),(LO).w); \
        (HI).x = fmaf((WW), __uint_as_float((unsigned)(ZZ).z << 16),        (HI).x); \
        (HI).y = fmaf((WW), __uint_as_float((unsigned)(ZZ).z & 0xFFFF0000u),(HI).y); \
        (HI).z = fmaf((WW), __uint_as_float((unsigned)(ZZ).w << 16),        (HI).z); \
        (HI).w = fmaf((WW), __uint_as_float((unsigned)(ZZ).w & 0xFFFF0000u),(HI).w); \
    } while (0)

    const int node0 = (int)blockIdx.x * NPB + wv * 8;
#pragma unroll 1
    for (int r = 0; r < 8; ++r) {
        const int node = node0 + r;
        if (node >= N) break;
        const int  deg  = gcnt[node];                 // wave-uniform
        const int2* slab = csr + ((size_t)node << CAPSH);

        float4 lo = float4{0,0,0,0}, hi = float4{0,0,0,0};

        const int jb = slot, j1 = slot + 8, j2 = slot + 16;
        int2 e0 = make_int2(0, 0), e1 = make_int2(0, 0), e2 = make_int2(0, 0);
        if (jb < deg) e0 = slab[jb];
        if (j1 < deg) e1 = slab[j1];
        if (j2 < deg) e2 = slab[j2];
        int4 z0 = make_int4(0,0,0,0), z1 = make_int4(0,0,0,0), z2 = make_int4(0,0,0,0);
        if (jb < deg) z0 = Zq[(size_t)e0.x * 8 + q];
        if (j1 < deg) z1 = Zq[(size_t)e1.x * 8 + q];
        if (j2 < deg) z2 = Zq[(size_t)e2.x * 8 + q];
        FMA8(lo, hi, __int_as_float(e0.y), z0);
        FMA8(lo, hi, __int_as_float(e1.y), z1);
        FMA8(lo, hi, __int_as_float(e2.y), z2);
        for (int j = j2 + 8; j < deg; j += 8) {       // tail (deg > 24, rare)
            int2 e = slab[j];
            int4 zz = Zq[(size_t)e.x * 8 + q];
            FMA8(lo, hi, __int_as_float(e.y), zz);
        }

        // cross-slot reduce (slots are 8 lanes apart) + coalesced store
#pragma unroll
        for (int off = 32; off >= 8; off >>= 1) {
            lo.x += __shfl_down(lo.x, off, 64);
            lo.y += __shfl_down(lo.y, off, 64);
            lo.z += __shfl_down(lo.z, off, 64);
            lo.w += __shfl_down(lo.w, off, 64);
            hi.x += __shfl_down(hi.x, off, 64);
            hi.y += __shfl_down(hi.y, off, 64);
            hi.z += __shfl_down(hi.z, off, 64);
            hi.w += __shfl_down(hi.w, off, 64);
        }
        if (lane < 8) {
            float4 o0, o1;
            o0.x = fmaxf(lo.x, 0.f); o0.y = fmaxf(lo.y, 0.f);
            o0.z = fmaxf(lo.z, 0.f); o0.w = fmaxf(lo.w, 0.f);
            o1.x = fmaxf(hi.x, 0.f); o1.y = fmaxf(hi.y, 0.f);
            o1.z = fmaxf(hi.z, 0.f); o1.w = fmaxf(hi.w, 0.f);
            float4* orow = reinterpret_cast<float4*>(out) + (size_t)node * 16 + lane * 2;
            orow[0] = o0;
            orow[1] = o1;
        }
    }
#undef FMA8
}

// ---------------------------------------------------------------------------
extern "C" void kernel_launch(void* const* d_in, const int* in_sizes, int n_in,
                              void* d_out, int out_size, void* d_ws, size_t ws_size,
                              hipStream_t stream)
{
    const float* emb  = (const float*)d_in[0];  // [N, 64]
    const int*   esrc = (const int*)  d_in[1];  // [E]
    const int*   edst = (const int*)  d_in[2];  // [E]
    const float* ew   = (const float*)d_in[3];  // [E]
    const float* W    = (const float*)d_in[4];  // [64, 64]
    float*       out  = (float*)d_out;          // [N, 64]

    const int N = in_sizes[0] / D;
    const int E = in_sizes[1];

    const int NC        = (E + CH - 1) / CH;     // 196 chunks
    const int gemmTiles = (N + 63) / 64;         // 782
    const int aggBlocks = (N + NPB - 1) / NPB;   // 1563

    // Workspace (~32.2 MB), all segments 16 B aligned.
    char* p = (char*)d_ws;
    __hip_bfloat16* Zb = (__hip_bfloat16*)p;  p += (size_t)N * D * 2;      // 6.4 MB
    int*  gcnt = (int*)p;                     p += (size_t)((N + 3) & ~3) * 4; // 200 KB
    int2* csr  = (int2*)p;                    // N * CAP * 8 = 25.6 MB

    hipMemsetAsync(gcnt, 0, (size_t)N * sizeof(int), stream);

    front<<<NC + gemmTiles, 256, 0, stream>>>(
        emb, W, Zb, esrc, edst, ew, gcnt, csr, N, E, NC);

    aggregate<<<aggBlocks, 256, 0, stream>>>(
        Zb, csr, gcnt, out, N);
}

// Round 9
// 131.757 us; speedup vs baseline: 1.0995x; 1.0995x over previous
//
#include <hip/hip_runtime.h>
#include <hip/hip_bf16.h>

#define D       64    // feature dim == units
#define CH      4096  // edges per chunk (bin/stage)
#define BKT     32    // nodes per bucket (aggregate)
#define PASS    1024  // edges staged per pass in aggregate
#define NCOL    16    // reservation-counter colors (chunk & 15)
#define COLMASK 15
#define SCAP    128   // slab capacity per (color,bucket): mean 32, ~17-sigma
#define SCAPSH  7     // log2(SCAP)

// ---------------------------------------------------------------------------
// front: blocks [0,NC): per-chunk LDS bucket-sort + ONE global atomicAdd per
// (block,bucket) into color-striped counters (R6-verified body, 127.6us).
// Blocks [NC,NC+gemmBlocks): GEMM, grid-strided 2 tiles/block (fewer
// dispatch generations of exposed per-block latency).
// rec.x = src(16) | dl(5)<<16 | bkt(11)<<21   (N < 65536, NB < 2048).
// ---------------------------------------------------------------------------
__global__ __launch_bounds__(256) void front(
    const float* __restrict__ emb,
    const float* __restrict__ W,
    __hip_bfloat16* __restrict__ Zb,
    const int*   __restrict__ src,
    const int*   __restrict__ dst,
    const float* __restrict__ w,
    int*         __restrict__ gcnt,   // [NCOL*NB], pre-zeroed by memset
    int2*        __restrict__ csr,    // [NCOL*NB*SCAP] slabs, color-major
    int N, int E, int NB, int NC, int gemmTiles, int gemmBlocks)
{
    __shared__ int2 rec[CH];       // 32 KB (GEMM branch aliases 16 KB as At)
    __shared__ int  lcnt[1568];    // 6.3 KB
    __shared__ int  sh[256];       // 1 KB

    const int t = threadIdx.x;

    if ((int)blockIdx.x < NC) {
        const int c     = blockIdx.x;
        const int color = c & COLMASK;
        const int e0    = c * CH;
        const int cnt   = min(CH, E - e0);   // multiple of 4 (E%4==0)

        for (int b = t; b < NB; b += 256) lcnt[b] = 0;
        __syncthreads();

        // ---- load + count-with-return (16 edges/thread, vector loads) ----
        int2 myrec[16]; int mypos[16];
        const int4*   s4p = reinterpret_cast<const int4*>(src + e0);
        const int4*   d4p = reinterpret_cast<const int4*>(dst + e0);
        const float4* w4p = reinterpret_cast<const float4*>(w + e0);
#pragma unroll
        for (int i = 0; i < 4; ++i) {
            int g = i * 256 + t;
            if (g * 4 < cnt) {
                int4   s4 = s4p[g];
                int4   d4 = d4p[g];
                float4 w4 = w4p[g];
                int b0 = d4.x >> 5, b1 = d4.y >> 5, b2 = d4.z >> 5, b3 = d4.w >> 5;
                myrec[4*i+0] = make_int2(s4.x | ((d4.x & 31) << 16) | (b0 << 21), __float_as_int(w4.x));
                myrec[4*i+1] = make_int2(s4.y | ((d4.y & 31) << 16) | (b1 << 21), __float_as_int(w4.y));
                myrec[4*i+2] = make_int2(s4.z | ((d4.z & 31) << 16) | (b2 << 21), __float_as_int(w4.z));
                myrec[4*i+3] = make_int2(s4.w | ((d4.w & 31) << 16) | (b3 << 21), __float_as_int(w4.w));
                mypos[4*i+0] = atomicAdd(&lcnt[b0], 1);
                mypos[4*i+1] = atomicAdd(&lcnt[b1], 1);
                mypos[4*i+2] = atomicAdd(&lcnt[b2], 1);
                mypos[4*i+3] = atomicAdd(&lcnt[b3], 1);
            } else {
#pragma unroll
                for (int k = 0; k < 4; ++k) mypos[4*i+k] = -1;
            }
        }
        __syncthreads();

        // ---- per-bucket counts; ISSUE striped reservation atomics early --
        int hv[7], ps[7], gbase[7];
        const int hbase = t * 7;
#pragma unroll
        for (int k = 0; k < 7; ++k) {
            int b = hbase + k;
            hv[k] = (b < NB) ? lcnt[b] : 0;
        }
#pragma unroll
        for (int k = 0; k < 7; ++k)
            gbase[k] = (hv[k] > 0)
                ? atomicAdd(&gcnt[color * NB + hbase + k], hv[k]) : 0;

        // ---- local exclusive scan of counts (for LDS staging layout) -----
        int s = 0;
#pragma unroll
        for (int k = 0; k < 7; ++k) { ps[k] = s; s += hv[k]; }
        sh[t] = s;
        __syncthreads();
        for (int off = 1; off < 256; off <<= 1) {
            int x = (t >= off) ? sh[t - off] : 0;
            __syncthreads();
            sh[t] += x;
            __syncthreads();
        }
        const int hexcl = sh[t] - s;
        __syncthreads();                       // all reads of lcnt done
#pragma unroll
        for (int k = 0; k < 7; ++k) {
            int b = hbase + k;
            if (b < NB) lcnt[b] = hexcl + ps[k];   // localBase
        }
        __syncthreads();

        // ---- stage records sorted by bucket ------------------------------
#pragma unroll
        for (int k = 0; k < 16; ++k) {
            if (mypos[k] >= 0)
                rec[lcnt[(unsigned)myrec[k].x >> 21] + mypos[k]] = myrec[k];
        }
        __syncthreads();

        // ---- lcnt[b] := slabStart(color,b) + gbase - localBase -----------
#pragma unroll
        for (int k = 0; k < 7; ++k) {
            int b = hbase + k;
            if (b < NB)
                lcnt[b] = ((color * NB + b) << SCAPSH) + gbase[k] - (hexcl + ps[k]);
        }
        __syncthreads();

        // ---- bulk write: run of bucket b lands at its reserved slab slot -
        for (int j = t; j < cnt; j += 256) {
            int2 rj = rec[j];
            csr[j + lcnt[(unsigned)rj.x >> 21]] = rj;
        }
        return;
    }

    // ---- GEMM branch: grid-stride tiles, proven R0 body per tile ----------
    float* At = (float*)rec;   // 16 KB alias
    const int lane = t & 63;
    const int wave = t >> 6;

    float wcol[D];
#pragma unroll
    for (int k = 0; k < D; ++k) wcol[k] = W[k * D + lane];

    for (int tile = (int)blockIdx.x - NC; tile < gemmTiles; tile += gemmBlocks) {
        const int row0 = tile * 64;

        for (int i = t; i < 1024; i += 256) {
            int r = i >> 4, gr = row0 + r;
            float4 v = (gr < N)
                ? reinterpret_cast<const float4*>(emb)[(size_t)gr * 16 + (i & 15)]
                : float4{0.f, 0.f, 0.f, 0.f};
            reinterpret_cast<float4*>(At)[i] = v;
        }
        __syncthreads();

        for (int rr = 0; rr < 16; ++rr) {
            int r = wave * 16 + rr, gr = row0 + r;
            if (gr >= N) break;
            const float4* arow = reinterpret_cast<const float4*>(At + r * D);
            float acc = 0.f;
#pragma unroll
            for (int k4 = 0; k4 < 16; ++k4) {
                float4 a = arow[k4];
                acc = fmaf(a.x, wcol[4 * k4 + 0], acc);
                acc = fmaf(a.y, wcol[4 * k4 + 1], acc);
                acc = fmaf(a.z, wcol[4 * k4 + 2], acc);
                acc = fmaf(a.w, wcol[4 * k4 + 3], acc);
            }
            Zb[(size_t)gr * D + lane] = __float2bfloat16(acc);
        }
        __syncthreads();   // LDS reuse across grid-stride tiles
    }
}

// ---------------------------------------------------------------------------
// aggregate: one block per 32-node bucket, color-segmented slab load + LDS
// sort by node (R6-verified), with two latency fixes:
//   (1) cpre built by 16 parallel threads + shfl scan (was 16 serial loads
//       by thread 0 at every block head);
//   (2) gather processes node PAIRS concurrently — 2 independent LDS->L2
//       dependent chains in flight instead of 1 (was 8 serial nodes/wave).
// ---------------------------------------------------------------------------
__global__ __launch_bounds__(256) void aggregate(
    const __hip_bfloat16* __restrict__ Zb,
    const int2* __restrict__ csr,
    const int*  __restrict__ gcnt,
    float*      __restrict__ out,
    int N, int NB)
{
    __shared__ int2 srec[PASS];   // 8 KB
    __shared__ int  hist[BKT];
    __shared__ int  nbase[BKT + 1];
    __shared__ int  cpre[NCOL + 1];

    const int t = threadIdx.x;
    const int b = blockIdx.x;

    if (t < NCOL) {                       // parallel cpre (lanes 0..15, wave 0)
        int v = gcnt[t * NB + b];
        int x = v;
#pragma unroll
        for (int off = 1; off < NCOL; off <<= 1) {
            int y = __shfl_up(x, off, 64);
            if (t >= off) x += y;
        }
        cpre[t] = x - v;
        if (t == NCOL - 1) cpre[NCOL] = x;
    }
    __syncthreads();
    const int T = cpre[NCOL];

    const int wv = t >> 6, lane = t & 63, slot = lane >> 3, q = lane & 7;
    const int4* Zq = reinterpret_cast<const int4*>(Zb);   // bf16 row = 8 int4

#define FMA8(LO, HI, WW, ZZ)                                                     \
    do {                                                                         \
        (LO).x = fmaf((WW), __uint_as_float((unsigned)(ZZ).x << 16),        (LO).x); \
        (LO).y = fmaf((WW), __uint_as_float((unsigned)(ZZ).x & 0xFFFF0000u),(LO).y); \
        (LO).z = fmaf((WW), __uint_as_float((unsigned)(ZZ).y << 16),        (LO).z); \
        (LO).w = fmaf((WW), __uint_as_float((unsigned)(ZZ).y & 0xFFFF0000u),(LO).w); \
        (HI).x = fmaf((WW), __uint_as_float((unsigned)(ZZ).z << 16),        (HI).x); \
        (HI).y = fmaf((WW), __uint_as_float((unsigned)(ZZ).z & 0xFFFF0000u),(HI).y); \
        (HI).z = fmaf((WW), __uint_as_float((unsigned)(ZZ).w << 16),        (HI).z); \
        (HI).w = fmaf((WW), __uint_as_float((unsigned)(ZZ).w & 0xFFFF0000u),(HI).w); \
    } while (0)

    float4 accLo[8], accHi[8];            // per-node results for this wave
#pragma unroll
    for (int r = 0; r < 8; ++r) { accLo[r] = float4{0,0,0,0}; accHi[r] = float4{0,0,0,0}; }

    for (int cur = 0; cur < T; cur += PASS) {
        const int cnt = min(PASS, T - cur);
        if (t < BKT) hist[t] = 0;
        __syncthreads();

        int2 myrec[4]; int mypos[4];
#pragma unroll
        for (int k = 0; k < 4; ++k) {
            int j = k * 256 + t;
            if (j < cnt) {
                int vj = cur + j;
                int kk = 0;
#pragma unroll
                for (int m = 1; m < NCOL; ++m) kk += (vj >= cpre[m]);
                int2 r2 = csr[((kk * NB + b) << SCAPSH) + (vj - cpre[kk])];
                myrec[k] = r2;
                mypos[k] = atomicAdd(&hist[(r2.x >> 16) & (BKT - 1)], 1);
            } else mypos[k] = -1;
        }
        __syncthreads();

        if (t < BKT) {
            int v = hist[t], x = v;
            for (int off = 1; off < BKT; off <<= 1) {
                int y = __shfl_up(x, off, 64);
                if (t >= off) x += y;
            }
            nbase[t] = x - v;
            if (t == BKT - 1) nbase[BKT] = x;
        }
        __syncthreads();

#pragma unroll
        for (int k = 0; k < 4; ++k) {
            if (mypos[k] >= 0)
                srec[nbase[(myrec[k].x >> 16) & (BKT - 1)] + mypos[k]] = myrec[k];
        }
        __syncthreads();

        // gather: wave wv owns nodes [wv*8, wv*8+8), processed in PAIRS
        for (int rp = 0; rp < 8; rp += 2) {
            const int nlA = wv * 8 + rp;
            const int nlB = nlA + 1;
            const int jbA = nbase[nlA] + slot, jeA = nbase[nlA + 1];
            const int jbB = nbase[nlB] + slot, jeB = nbase[nlB + 1];
            const int a1 = jbA + 8, a2 = jbA + 16;
            const int b1 = jbB + 8, b2 = jbB + 16;

            int2 eA0{0,0}, eA1{0,0}, eA2{0,0}, eB0{0,0}, eB1{0,0}, eB2{0,0};
            if (jbA < jeA) eA0 = srec[jbA];
            if (a1  < jeA) eA1 = srec[a1];
            if (a2  < jeA) eA2 = srec[a2];
            if (jbB < jeB) eB0 = srec[jbB];
            if (b1  < jeB) eB1 = srec[b1];
            if (b2  < jeB) eB2 = srec[b2];

            int4 zA0{0,0,0,0}, zA1{0,0,0,0}, zA2{0,0,0,0};
            int4 zB0{0,0,0,0}, zB1{0,0,0,0}, zB2{0,0,0,0};
            if (jbA < jeA) zA0 = Zq[(size_t)(eA0.x & 0xFFFF) * 8 + q];
            if (jbB < jeB) zB0 = Zq[(size_t)(eB0.x & 0xFFFF) * 8 + q];
            if (a1  < jeA) zA1 = Zq[(size_t)(eA1.x & 0xFFFF) * 8 + q];
            if (b1  < jeB) zB1 = Zq[(size_t)(eB1.x & 0xFFFF) * 8 + q];
            if (a2  < jeA) zA2 = Zq[(size_t)(eA2.x & 0xFFFF) * 8 + q];
            if (b2  < jeB) zB2 = Zq[(size_t)(eB2.x & 0xFFFF) * 8 + q];

            FMA8(accLo[rp],   accHi[rp],   __int_as_float(eA0.y), zA0);
            FMA8(accLo[rp+1], accHi[rp+1], __int_as_float(eB0.y), zB0);
            FMA8(accLo[rp],   accHi[rp],   __int_as_float(eA1.y), zA1);
            FMA8(accLo[rp+1], accHi[rp+1], __int_as_float(eB1.y), zB1);
            FMA8(accLo[rp],   accHi[rp],   __int_as_float(eA2.y), zA2);
            FMA8(accLo[rp+1], accHi[rp+1], __int_as_float(eB2.y), zB2);

            for (int j = a2 + 8; j < jeA; j += 8) {    // tail A (deg > 24)
                int2 e = srec[j];
                int4 zz = Zq[(size_t)(e.x & 0xFFFF) * 8 + q];
                FMA8(accLo[rp], accHi[rp], __int_as_float(e.y), zz);
            }
            for (int j = b2 + 8; j < jeB; j += 8) {    // tail B
                int2 e = srec[j];
                int4 zz = Zq[(size_t)(e.x & 0xFFFF) * 8 + q];
                FMA8(accLo[rp+1], accHi[rp+1], __int_as_float(e.y), zz);
            }
        }
        __syncthreads();
    }

    // reduce the 8 slots + store (8 lanes x 32 B = coalesced 256 B row)
    const int node0 = b * BKT + wv * 8;
#pragma unroll
    for (int r = 0; r < 8; ++r) {
        float4 lo = accLo[r], hi = accHi[r];
#pragma unroll
        for (int off = 32; off >= 8; off >>= 1) {
            lo.x += __shfl_down(lo.x, off, 64);
            lo.y += __shfl_down(lo.y, off, 64);
            lo.z += __shfl_down(lo.z, off, 64);
            lo.w += __shfl_down(lo.w, off, 64);
            hi.x += __shfl_down(hi.x, off, 64);
            hi.y += __shfl_down(hi.y, off, 64);
            hi.z += __shfl_down(hi.z, off, 64);
            hi.w += __shfl_down(hi.w, off, 64);
        }
        int node = node0 + r;
        if (lane < 8 && node < N) {
            float4 o0, o1;
            o0.x = fmaxf(lo.x, 0.f); o0.y = fmaxf(lo.y, 0.f);
            o0.z = fmaxf(lo.z, 0.f); o0.w = fmaxf(lo.w, 0.f);
            o1.x = fmaxf(hi.x, 0.f); o1.y = fmaxf(hi.y, 0.f);
            o1.z = fmaxf(hi.z, 0.f); o1.w = fmaxf(hi.w, 0.f);
            float4* orow = reinterpret_cast<float4*>(out) + (size_t)node * 16 + lane * 2;
            orow[0] = o0;
            orow[1] = o1;
        }
    }
#undef FMA8
}

// ---------------------------------------------------------------------------
extern "C" void kernel_launch(void* const* d_in, const int* in_sizes, int n_in,
                              void* d_out, int out_size, void* d_ws, size_t ws_size,
                              hipStream_t stream)
{
    const float* emb  = (const float*)d_in[0];  // [N, 64]
    const int*   esrc = (const int*)  d_in[1];  // [E]
    const int*   edst = (const int*)  d_in[2];  // [E]
    const float* ew   = (const float*)d_in[3];  // [E]
    const float* W    = (const float*)d_in[4];  // [64, 64]
    float*       out  = (float*)d_out;          // [N, 64]

    const int N = in_sizes[0] / D;
    const int E = in_sizes[1];

    const int NB         = (N + BKT - 1) / BKT;     // 1563 buckets
    const int NC         = (E + CH - 1) / CH;       // 196 chunks
    const int gemmTiles  = (N + 63) / 64;           // 782
    const int gemmBlocks = (gemmTiles + 1) / 2;     // 391 (2 tiles/block)

    // Workspace (~32 MB), all segments 16 B aligned.
    char* p = (char*)d_ws;
    __hip_bfloat16* Zb = (__hip_bfloat16*)p;  p += (size_t)N * D * 2;        // 6.4 MB
    int*  gcnt = (int*)p;                     p += (size_t)NCOL * ((NB + 3) & ~3) * 4; // 100 KB
    int2* csr  = (int2*)p;                    // NCOL * NB * SCAP * 8 = 25.6 MB

    hipMemsetAsync(gcnt, 0, (size_t)NCOL * NB * sizeof(int), stream);

    front<<<NC + gemmBlocks, 256, 0, stream>>>(
        emb, W, Zb, esrc, edst, ew, gcnt, csr, N, E, NB, NC, gemmTiles, gemmBlocks);

    aggregate<<<NB, 256, 0, stream>>>(
        Zb, csr, gcnt, out, N, NB);
}

// Round 10
// 127.039 us; speedup vs baseline: 1.1404x; 1.0371x over previous
//
#include <hip/hip_runtime.h>
#include <hip/hip_bf16.h>

#define D       64    // feature dim == units
#define CH      4096  // edges per chunk (bin/stage)
#define BKT     32    // nodes per bucket (aggregate)
#define PASS    1024  // edges staged per pass in aggregate
#define NCOL    16    // reservation-counter colors (chunk & 15)
#define COLMASK 15
#define SCAP    128   // slab capacity per (color,bucket): mean 32, ~17-sigma
#define SCAPSH  7     // log2(SCAP)

// ---------------------------------------------------------------------------
// front: R6-verified body (127.6us config), byte-identical.
// Blocks [0,NC): per-chunk LDS bucket-sort + ONE global atomicAdd per
// (block,bucket) into color-striped counters.  Blocks [NC,NC+gemmTiles):
// ONE GEMM tile per block (R9's 2-tiles/block serialization reverted).
// rec.x = src(16) | dl(5)<<16 | bkt(11)<<21   (N < 65536, NB < 2048).
// ---------------------------------------------------------------------------
__global__ __launch_bounds__(256) void front(
    const float* __restrict__ emb,
    const float* __restrict__ W,
    __hip_bfloat16* __restrict__ Zb,
    const int*   __restrict__ src,
    const int*   __restrict__ dst,
    const float* __restrict__ w,
    int*         __restrict__ gcnt,   // [NCOL*NB], pre-zeroed by memset
    int2*        __restrict__ csr,    // [NCOL*NB*SCAP] slabs, color-major
    int N, int E, int NB, int NC)
{
    __shared__ int2 rec[CH];       // 32 KB (GEMM branch aliases 16 KB as At)
    __shared__ int  lcnt[1568];    // 6.3 KB
    __shared__ int  sh[256];       // 1 KB

    const int t = threadIdx.x;

    if ((int)blockIdx.x < NC) {
        const int c     = blockIdx.x;
        const int color = c & COLMASK;
        const int e0    = c * CH;
        const int cnt   = min(CH, E - e0);   // multiple of 4 (E%4==0)

        for (int b = t; b < NB; b += 256) lcnt[b] = 0;
        __syncthreads();

        // ---- load + count-with-return (16 edges/thread, vector loads) ----
        int2 myrec[16]; int mypos[16];
        const int4*   s4p = reinterpret_cast<const int4*>(src + e0);
        const int4*   d4p = reinterpret_cast<const int4*>(dst + e0);
        const float4* w4p = reinterpret_cast<const float4*>(w + e0);
#pragma unroll
        for (int i = 0; i < 4; ++i) {
            int g = i * 256 + t;
            if (g * 4 < cnt) {
                int4   s4 = s4p[g];
                int4   d4 = d4p[g];
                float4 w4 = w4p[g];
                int b0 = d4.x >> 5, b1 = d4.y >> 5, b2 = d4.z >> 5, b3 = d4.w >> 5;
                myrec[4*i+0] = make_int2(s4.x | ((d4.x & 31) << 16) | (b0 << 21), __float_as_int(w4.x));
                myrec[4*i+1] = make_int2(s4.y | ((d4.y & 31) << 16) | (b1 << 21), __float_as_int(w4.y));
                myrec[4*i+2] = make_int2(s4.z | ((d4.z & 31) << 16) | (b2 << 21), __float_as_int(w4.z));
                myrec[4*i+3] = make_int2(s4.w | ((d4.w & 31) << 16) | (b3 << 21), __float_as_int(w4.w));
                mypos[4*i+0] = atomicAdd(&lcnt[b0], 1);
                mypos[4*i+1] = atomicAdd(&lcnt[b1], 1);
                mypos[4*i+2] = atomicAdd(&lcnt[b2], 1);
                mypos[4*i+3] = atomicAdd(&lcnt[b3], 1);
            } else {
#pragma unroll
                for (int k = 0; k < 4; ++k) mypos[4*i+k] = -1;
            }
        }
        __syncthreads();

        // ---- per-bucket counts; ISSUE striped reservation atomics early --
        int hv[7], ps[7], gbase[7];
        const int hbase = t * 7;
#pragma unroll
        for (int k = 0; k < 7; ++k) {
            int b = hbase + k;
            hv[k] = (b < NB) ? lcnt[b] : 0;
        }
#pragma unroll
        for (int k = 0; k < 7; ++k)
            gbase[k] = (hv[k] > 0)
                ? atomicAdd(&gcnt[color * NB + hbase + k], hv[k]) : 0;

        // ---- local exclusive scan of counts (for LDS staging layout) -----
        int s = 0;
#pragma unroll
        for (int k = 0; k < 7; ++k) { ps[k] = s; s += hv[k]; }
        sh[t] = s;
        __syncthreads();
        for (int off = 1; off < 256; off <<= 1) {
            int x = (t >= off) ? sh[t - off] : 0;
            __syncthreads();
            sh[t] += x;
            __syncthreads();
        }
        const int hexcl = sh[t] - s;
        __syncthreads();                       // all reads of lcnt done
#pragma unroll
        for (int k = 0; k < 7; ++k) {
            int b = hbase + k;
            if (b < NB) lcnt[b] = hexcl + ps[k];   // localBase
        }
        __syncthreads();

        // ---- stage records sorted by bucket ------------------------------
#pragma unroll
        for (int k = 0; k < 16; ++k) {
            if (mypos[k] >= 0)
                rec[lcnt[(unsigned)myrec[k].x >> 21] + mypos[k]] = myrec[k];
        }
        __syncthreads();

        // ---- lcnt[b] := slabStart(color,b) + gbase - localBase -----------
#pragma unroll
        for (int k = 0; k < 7; ++k) {
            int b = hbase + k;
            if (b < NB)
                lcnt[b] = ((color * NB + b) << SCAPSH) + gbase[k] - (hexcl + ps[k]);
        }
        __syncthreads();

        // ---- bulk write: run of bucket b lands at its reserved slab slot -
        for (int j = t; j < cnt; j += 256) {
            int2 rj = rec[j];
            csr[j + lcnt[(unsigned)rj.x >> 21]] = rj;
        }
        return;
    }

    // ---- GEMM branch: tile (blockIdx.x - NC), proven R0 body --------------
    float* At = (float*)rec;   // 16 KB alias
    const int row0 = ((int)blockIdx.x - NC) * 64;
    const int lane = t & 63;
    const int wave = t >> 6;

    float wcol[D];
#pragma unroll
    for (int k = 0; k < D; ++k) wcol[k] = W[k * D + lane];

    for (int i = t; i < 1024; i += 256) {
        int r = i >> 4, gr = row0 + r;
        float4 v = (gr < N)
            ? reinterpret_cast<const float4*>(emb)[(size_t)gr * 16 + (i & 15)]
            : float4{0.f, 0.f, 0.f, 0.f};
        reinterpret_cast<float4*>(At)[i] = v;
    }
    __syncthreads();

    for (int rr = 0; rr < 16; ++rr) {
        int r = wave * 16 + rr, gr = row0 + r;
        if (gr >= N) break;
        const float4* arow = reinterpret_cast<const float4*>(At + r * D);
        float acc = 0.f;
#pragma unroll
        for (int k4 = 0; k4 < 16; ++k4) {
            float4 a = arow[k4];
            acc = fmaf(a.x, wcol[4 * k4 + 0], acc);
            acc = fmaf(a.y, wcol[4 * k4 + 1], acc);
            acc = fmaf(a.z, wcol[4 * k4 + 2], acc);
            acc = fmaf(a.w, wcol[4 * k4 + 3], acc);
        }
        Zb[(size_t)gr * D + lane] = __float2bfloat16(acc);
    }
}

// ---------------------------------------------------------------------------
// aggregate: R9-verified body (replay <43.7us vs R6's 51.5us), byte-identical.
// One block per 32-node bucket; parallel cpre via 16-lane shfl scan; LDS sort
// by node; gather processes node PAIRS (2 independent load chains in flight).
// ---------------------------------------------------------------------------
__global__ __launch_bounds__(256) void aggregate(
    const __hip_bfloat16* __restrict__ Zb,
    const int2* __restrict__ csr,
    const int*  __restrict__ gcnt,
    float*      __restrict__ out,
    int N, int NB)
{
    __shared__ int2 srec[PASS];   // 8 KB
    __shared__ int  hist[BKT];
    __shared__ int  nbase[BKT + 1];
    __shared__ int  cpre[NCOL + 1];

    const int t = threadIdx.x;
    const int b = blockIdx.x;

    if (t < NCOL) {                       // parallel cpre (lanes 0..15, wave 0)
        int v = gcnt[t * NB + b];
        int x = v;
#pragma unroll
        for (int off = 1; off < NCOL; off <<= 1) {
            int y = __shfl_up(x, off, 64);
            if (t >= off) x += y;
        }
        cpre[t] = x - v;
        if (t == NCOL - 1) cpre[NCOL] = x;
    }
    __syncthreads();
    const int T = cpre[NCOL];

    const int wv = t >> 6, lane = t & 63, slot = lane >> 3, q = lane & 7;
    const int4* Zq = reinterpret_cast<const int4*>(Zb);   // bf16 row = 8 int4

#define FMA8(LO, HI, WW, ZZ)                                                     \
    do {                                                                         \
        (LO).x = fmaf((WW), __uint_as_float((unsigned)(ZZ).x << 16),        (LO).x); \
        (LO).y = fmaf((WW), __uint_as_float((unsigned)(ZZ).x & 0xFFFF0000u),(LO).y); \
        (LO).z = fmaf((WW), __uint_as_float((unsigned)(ZZ).y << 16),        (LO).z); \
        (LO).w = fmaf((WW), __uint_as_float((unsigned)(ZZ).y & 0xFFFF0000u),(LO).w); \
        (HI).x = fmaf((WW), __uint_as_float((unsigned)(ZZ).z << 16),        (HI).x); \
        (HI).y = fmaf((WW), __uint_as_float((unsigned)(ZZ).z & 0xFFFF0000u),(HI).y); \
        (HI).z = fmaf((WW), __uint_as_float((unsigned)(ZZ).w << 16),        (HI).z); \
        (HI).w = fmaf((WW), __uint_as_float((unsigned)(ZZ).w & 0xFFFF0000u),(HI).w); \
    } while (0)

    float4 accLo[8], accHi[8];            // per-node results for this wave
#pragma unroll
    for (int r = 0; r < 8; ++r) { accLo[r] = float4{0,0,0,0}; accHi[r] = float4{0,0,0,0}; }

    for (int cur = 0; cur < T; cur += PASS) {
        const int cnt = min(PASS, T - cur);
        if (t < BKT) hist[t] = 0;
        __syncthreads();

        int2 myrec[4]; int mypos[4];
#pragma unroll
        for (int k = 0; k < 4; ++k) {
            int j = k * 256 + t;
            if (j < cnt) {
                int vj = cur + j;
                int kk = 0;
#pragma unroll
                for (int m = 1; m < NCOL; ++m) kk += (vj >= cpre[m]);
                int2 r2 = csr[((kk * NB + b) << SCAPSH) + (vj - cpre[kk])];
                myrec[k] = r2;
                mypos[k] = atomicAdd(&hist[(r2.x >> 16) & (BKT - 1)], 1);
            } else mypos[k] = -1;
        }
        __syncthreads();

        if (t < BKT) {
            int v = hist[t], x = v;
            for (int off = 1; off < BKT; off <<= 1) {
                int y = __shfl_up(x, off, 64);
                if (t >= off) x += y;
            }
            nbase[t] = x - v;
            if (t == BKT - 1) nbase[BKT] = x;
        }
        __syncthreads();

#pragma unroll
        for (int k = 0; k < 4; ++k) {
            if (mypos[k] >= 0)
                srec[nbase[(myrec[k].x >> 16) & (BKT - 1)] + mypos[k]] = myrec[k];
        }
        __syncthreads();

        // gather: wave wv owns nodes [wv*8, wv*8+8), processed in PAIRS
        for (int rp = 0; rp < 8; rp += 2) {
            const int nlA = wv * 8 + rp;
            const int nlB = nlA + 1;
            const int jbA = nbase[nlA] + slot, jeA = nbase[nlA + 1];
            const int jbB = nbase[nlB] + slot, jeB = nbase[nlB + 1];
            const int a1 = jbA + 8, a2 = jbA + 16;
            const int b1 = jbB + 8, b2 = jbB + 16;

            int2 eA0{0,0}, eA1{0,0}, eA2{0,0}, eB0{0,0}, eB1{0,0}, eB2{0,0};
            if (jbA < jeA) eA0 = srec[jbA];
            if (a1  < jeA) eA1 = srec[a1];
            if (a2  < jeA) eA2 = srec[a2];
            if (jbB < jeB) eB0 = srec[jbB];
            if (b1  < jeB) eB1 = srec[b1];
            if (b2  < jeB) eB2 = srec[b2];

            int4 zA0{0,0,0,0}, zA1{0,0,0,0}, zA2{0,0,0,0};
            int4 zB0{0,0,0,0}, zB1{0,0,0,0}, zB2{0,0,0,0};
            if (jbA < jeA) zA0 = Zq[(size_t)(eA0.x & 0xFFFF) * 8 + q];
            if (jbB < jeB) zB0 = Zq[(size_t)(eB0.x & 0xFFFF) * 8 + q];
            if (a1  < jeA) zA1 = Zq[(size_t)(eA1.x & 0xFFFF) * 8 + q];
            if (b1  < jeB) zB1 = Zq[(size_t)(eB1.x & 0xFFFF) * 8 + q];
            if (a2  < jeA) zA2 = Zq[(size_t)(eA2.x & 0xFFFF) * 8 + q];
            if (b2  < jeB) zB2 = Zq[(size_t)(eB2.x & 0xFFFF) * 8 + q];

            FMA8(accLo[rp],   accHi[rp],   __int_as_float(eA0.y), zA0);
            FMA8(accLo[rp+1], accHi[rp+1], __int_as_float(eB0.y), zB0);
            FMA8(accLo[rp],   accHi[rp],   __int_as_float(eA1.y), zA1);
            FMA8(accLo[rp+1], accHi[rp+1], __int_as_float(eB1.y), zB1);
            FMA8(accLo[rp],   accHi[rp],   __int_as_float(eA2.y), zA2);
            FMA8(accLo[rp+1], accHi[rp+1], __int_as_float(eB2.y), zB2);

            for (int j = a2 + 8; j < jeA; j += 8) {    // tail A (deg > 24)
                int2 e = srec[j];
                int4 zz = Zq[(size_t)(e.x & 0xFFFF) * 8 + q];
                FMA8(accLo[rp], accHi[rp], __int_as_float(e.y), zz);
            }
            for (int j = b2 + 8; j < jeB; j += 8) {    // tail B
                int2 e = srec[j];
                int4 zz = Zq[(size_t)(e.x & 0xFFFF) * 8 + q];
                FMA8(accLo[rp+1], accHi[rp+1], __int_as_float(e.y), zz);
            }
        }
        __syncthreads();
    }

    // reduce the 8 slots + store (8 lanes x 32 B = coalesced 256 B row)
    const int node0 = b * BKT + wv * 8;
#pragma unroll
    for (int r = 0; r < 8; ++r) {
        float4 lo = accLo[r], hi = accHi[r];
#pragma unroll
        for (int off = 32; off >= 8; off >>= 1) {
            lo.x += __shfl_down(lo.x, off, 64);
            lo.y += __shfl_down(lo.y, off, 64);
            lo.z += __shfl_down(lo.z, off, 64);
            lo.w += __shfl_down(lo.w, off, 64);
            hi.x += __shfl_down(hi.x, off, 64);
            hi.y += __shfl_down(hi.y, off, 64);
            hi.z += __shfl_down(hi.z, off, 64);
            hi.w += __shfl_down(hi.w, off, 64);
        }
        int node = node0 + r;
        if (lane < 8 && node < N) {
            float4 o0, o1;
            o0.x = fmaxf(lo.x, 0.f); o0.y = fmaxf(lo.y, 0.f);
            o0.z = fmaxf(lo.z, 0.f); o0.w = fmaxf(lo.w, 0.f);
            o1.x = fmaxf(hi.x, 0.f); o1.y = fmaxf(hi.y, 0.f);
            o1.z = fmaxf(hi.z, 0.f); o1.w = fmaxf(hi.w, 0.f);
            float4* orow = reinterpret_cast<float4*>(out) + (size_t)node * 16 + lane * 2;
            orow[0] = o0;
            orow[1] = o1;
        }
    }
#undef FMA8
}

// ---------------------------------------------------------------------------
extern "C" void kernel_launch(void* const* d_in, const int* in_sizes, int n_in,
                              void* d_out, int out_size, void* d_ws, size_t ws_size,
                              hipStream_t stream)
{
    const float* emb  = (const float*)d_in[0];  // [N, 64]
    const int*   esrc = (const int*)  d_in[1];  // [E]
    const int*   edst = (const int*)  d_in[2];  // [E]
    const float* ew   = (const float*)d_in[3];  // [E]
    const float* W    = (const float*)d_in[4];  // [64, 64]
    float*       out  = (float*)d_out;          // [N, 64]

    const int N = in_sizes[0] / D;
    const int E = in_sizes[1];

    const int NB        = (N + BKT - 1) / BKT;   // 1563 buckets
    const int NC        = (E + CH - 1) / CH;     // 196 chunks
    const int gemmTiles = (N + 63) / 64;         // 782

    // Workspace (~32 MB), all segments 16 B aligned.
    char* p = (char*)d_ws;
    __hip_bfloat16* Zb = (__hip_bfloat16*)p;  p += (size_t)N * D * 2;        // 6.4 MB
    int*  gcnt = (int*)p;                     p += (size_t)NCOL * ((NB + 3) & ~3) * 4; // 100 KB
    int2* csr  = (int2*)p;                    // NCOL * NB * SCAP * 8 = 25.6 MB

    hipMemsetAsync(gcnt, 0, (size_t)NCOL * NB * sizeof(int), stream);

    front<<<NC + gemmTiles, 256, 0, stream>>>(
        emb, W, Zb, esrc, edst, ew, gcnt, csr, N, E, NB, NC);

    aggregate<<<NB, 256, 0, stream>>>(
        Zb, csr, gcnt, out, N, NB);
}